// Round 4
// baseline (292.877 us; speedup 1.0000x reference)
//
#include <hip/hip_runtime.h>

#define TBL 4096

// ---- f32 ws layout (floats) ----
#define WS_S    0
#define WS_AT   64
#define WS_BQT  576
#define WS_CT   1088
#define WS_C0   1152
#define WS_F32_END 1536
// ---- bf16 packed region (shorts), base = (short*)(ws + WS_F32_END) ----
#define PB_AT   0      // At[h][j]           512
#define PB_BQN  512    // -Bqt[h][j]         512
#define PB_CT   1024   // Ct[h][g]           64
#define PB_W2T  1088   // w2T[d][h]          512
#define PB_PW2T 1600   // pw2T[d][h]         512
#define PB_PW1  2112   // pw1T[h][j] (j<4)   64
#define PB_VT   2176   // Wv[n][j]           4096
#define PB_OWT  6272   // owT[e][d]          4096
#define PB_END  10368

typedef __attribute__((ext_vector_type(8))) short bf16x8;
typedef __attribute__((ext_vector_type(4))) float f32x4;

__device__ inline short f2bf(float f) {
    union { float f; unsigned u; } v; v.f = f;
    unsigned r = v.u + 0x7fffu + ((v.u >> 16) & 1u);
    return (short)(r >> 16);
}

__device__ inline bf16x8 pack8(const float* x) {
    bf16x8 r;
    #pragma unroll
    for (int i = 0; i < 8; ++i) r[i] = f2bf(x[i]);
    return r;
}

__device__ inline bf16x8 loadpack(const float* p) {
    float4 a = *(const float4*)p;
    float4 b = *(const float4*)(p + 4);
    float t[8] = {a.x, a.y, a.z, a.w, b.x, b.y, b.z, b.w};
    return pack8(t);
}

// truncating f32->bf16 pack: 1 v_perm per 2 elements
__device__ inline bf16x8 pack8t(float4 a, float4 b) {
    union { unsigned u[4]; bf16x8 v; } r;
    r.u[0] = __builtin_amdgcn_perm(__float_as_uint(a.y), __float_as_uint(a.x), 0x07060302u);
    r.u[1] = __builtin_amdgcn_perm(__float_as_uint(a.w), __float_as_uint(a.z), 0x07060302u);
    r.u[2] = __builtin_amdgcn_perm(__float_as_uint(b.y), __float_as_uint(b.x), 0x07060302u);
    r.u[3] = __builtin_amdgcn_perm(__float_as_uint(b.w), __float_as_uint(b.z), 0x07060302u);
    return r.v;
}

__global__ __launch_bounds__(256) void precompute_kernel(
    const float* __restrict__ strength, const float* __restrict__ str_w,
    const float* __restrict__ str_b,
    const float* __restrict__ q_tbl, const float* __restrict__ k_tbl,
    const float* __restrict__ attn_w1, const float* __restrict__ attn_b1,
    const float* __restrict__ pos_w2, const float* __restrict__ pos_b2,
    const int* __restrict__ embed_id, float* __restrict__ ws)
{
    __shared__ float red[4][64];
    const int t = threadIdx.x;
    const int blk = blockIdx.x;
    const int id = embed_id[0];
    if (blk == 0) {
        const int d = t & 63, part = t >> 6;
        float acc = 0.f;
        for (int i = part * 128; i < part * 128 + 128; ++i)
            acc += strength[i] * str_w[i * 64 + d];
        red[part][d] = acc;
        __syncthreads();
        if (t < 64)
            ws[WS_S + t] = red[0][t] + red[1][t] + red[2][t] + red[3][t] + str_b[t];
    } else if (blk <= 2) {
        const int h = (blk - 1) * 4 + (t >> 6);
        const int j = t & 63;
        const float* W = k_tbl + (size_t)id * TBL;
        float acc = 0.f;
        for (int d = 0; d < 64; ++d) acc += W[d * 64 + j] * attn_w1[d * 8 + h];
        ws[WS_AT + h * 64 + j] = acc;
    } else if (blk <= 4) {
        const int h = (blk - 3) * 4 + (t >> 6);
        const int j = t & 63;
        const float* W = q_tbl + (size_t)id * TBL;
        float acc = 0.f;
        for (int d = 0; d < 64; ++d) acc += W[d * 64 + j] * attn_w1[d * 8 + h];
        ws[WS_BQT + h * 64 + j] = acc;
    } else {
        if (t < 64) {
            const int h = t >> 3, g = t & 7;
            float acc = 0.f;
            for (int d = 0; d < 64; ++d) acc += pos_w2[g * 64 + d] * attn_w1[d * 8 + h];
            ws[WS_CT + t] = acc;
        } else if (t < 72) {
            const int h = t - 64;
            float acc = attn_b1[h];
            for (int d = 0; d < 64; ++d) acc += pos_b2[d] * attn_w1[d * 8 + h];
            ws[WS_C0 + h] = acc;
        }
    }
}

// Packs every weight into the bf16 fragment layouts the main kernel loads
// directly (contiguous 16B per lane). Runs after precompute_kernel.
__global__ __launch_bounds__(256) void pack_kernel(
    const float* __restrict__ v_tbl,
    const float* __restrict__ pos_w1, const float* __restrict__ pos_w2,
    const float* __restrict__ attn_w2, const float* __restrict__ out_w,
    const int* __restrict__ embed_id, float* __restrict__ ws)
{
    short* pk = (short*)(ws + WS_F32_END);
    const int i = blockIdx.x * 256 + threadIdx.x;
    if (i >= PB_END) return;
    const int id = embed_id[0];
    if (i < 512) {
        pk[i] = f2bf(ws[WS_AT + i]);
    } else if (i < 1024) {
        pk[i] = f2bf(-ws[WS_BQT + (i - 512)]);
    } else if (i < 1088) {
        pk[i] = f2bf(ws[WS_CT + (i - 1024)]);
    } else if (i < 1600) {
        const int idx = i - 1088, d = idx >> 3, h = idx & 7;
        pk[i] = f2bf(attn_w2[h * 64 + d]);
    } else if (i < 2112) {
        const int idx = i - 1600, d = idx >> 3, h = idx & 7;
        pk[i] = f2bf(pos_w2[h * 64 + d]);
    } else if (i < 2176) {
        const int idx = i - 2112, h = idx >> 3, j = idx & 7;
        pk[i] = (j < 4) ? f2bf(pos_w1[j * 8 + h]) : (short)0;
    } else if (i < 6272) {
        pk[i] = f2bf(v_tbl[(size_t)id * TBL + (i - 2176)]);
    } else {
        const int idx = i - 6272, e = idx >> 6, d = idx & 63;
        pk[i] = f2bf(out_w[d * 64 + e]);
    }
}

// One wave handles 16 bn (8 iterations x 2 bn). Per-wave LDS, no barriers.
// q-contribution hoisted to a pre-loop MFMA; k/pos/mask double-buffer
// prefetched; all weights loaded pre-packed bf16.
__global__ __launch_bounds__(256, 3) void attn2d_main(
    const float* __restrict__ q, const float* __restrict__ k,
    const float* __restrict__ pos,
    const float* __restrict__ pos_b1, const float* __restrict__ pos_b2,
    const float* __restrict__ attn_b2, const float* __restrict__ out_b,
    const int* __restrict__ mask,
    const float* __restrict__ ws, float* __restrict__ out)
{
    __shared__ __align__(16) short hp_bf[4][16 * 8];   // hp rows, bf16
    __shared__ __align__(16) short rh_bf[4][16 * 8];   // rhid rows, bf16
    __shared__ __align__(16) float qB_lds[4][16 * 8];  // -q.Bqt per wave-bn
    __shared__ __align__(16) short x_bf[4][16 * 72];   // x rows, bf16

    const int tid  = threadIdx.x;
    const int lane = tid & 63;
    const int wiv  = __builtin_amdgcn_readfirstlane(tid >> 6);
    const int q4   = lane >> 4;
    const int col  = lane & 15;

    short* hp_w = hp_bf[wiv];
    short* rh_w = rh_bf[wiv];
    float* qB_w = qB_lds[wiv];
    short* x_w  = x_bf[wiv];

    const int wid = blockIdx.x * 4 + wiv;     // 0..4095
    const short* pk = (const short*)(ws + WS_F32_END);
    const bf16x8 z{};

    // ---- persistent B-fragments: straight 16B bf16 loads ----
    bf16x8 Bv[4][2];
    #pragma unroll
    for (int t = 0; t < 4; ++t)
        #pragma unroll
        for (int c = 0; c < 2; ++c)
            Bv[t][c] = *(const bf16x8*)&pk[PB_VT + (t * 16 + col) * 64 + c * 32 + q4 * 8];
    bf16x8 Bh[2];
    #pragma unroll
    for (int c = 0; c < 2; ++c)
        Bh[c] = (col < 8) ? *(const bf16x8*)&pk[PB_AT + col * 64 + c * 32 + q4 * 8] : z;
    const bf16x8 Bct  = (q4 == 0 && col < 8) ? *(const bf16x8*)&pk[PB_CT + col * 8] : z;
    const bf16x8 Bpw1 = (q4 == 0 && col < 8) ? *(const bf16x8*)&pk[PB_PW1 + col * 8] : z;
    bf16x8 Bw2[4], Bpw2[4];
    #pragma unroll
    for (int t = 0; t < 4; ++t) {
        Bw2[t]  = (q4 == 0) ? *(const bf16x8*)&pk[PB_W2T  + (t * 16 + col) * 8] : z;
        Bpw2[t] = (q4 == 0) ? *(const bf16x8*)&pk[PB_PW2T + (t * 16 + col) * 8] : z;
    }

    // ---- per-lane constants ----
    float b2a4[4], sb4[4], ob4[4];
    #pragma unroll
    for (int t = 0; t < 4; ++t) {
        b2a4[t] = attn_b2[t * 16 + col];
        sb4[t]  = ws[WS_S + t * 16 + col] + pos_b2[t * 16 + col];
        ob4[t]  = out_b[t * 16 + col];
    }
    const float c0r = (col < 8) ? ws[WS_C0 + col] : 0.f;
    const float b1c = (col < 8) ? pos_b1[col] : 0.f;

    // ---- pre-phase: qB[16 wave-bn][8] = -q.Bqt via one 16-row MFMA pair ----
    {
        bf16x8 Bq0 = (col < 8) ? *(const bf16x8*)&pk[PB_BQN + col * 64 + q4 * 8] : z;
        bf16x8 Bq1 = (col < 8) ? *(const bf16x8*)&pk[PB_BQN + col * 64 + 32 + q4 * 8] : z;
        bf16x8 Aq0 = loadpack(q + (size_t)(wid * 16 + col) * 64 + q4 * 8);
        bf16x8 Aq1 = loadpack(q + (size_t)(wid * 16 + col) * 64 + 32 + q4 * 8);
        f32x4 aq = {0.f, 0.f, 0.f, 0.f};
        aq = __builtin_amdgcn_mfma_f32_16x16x32_bf16(Aq0, Bq0, aq, 0, 0, 0);
        aq = __builtin_amdgcn_mfma_f32_16x16x32_bf16(Aq1, Bq1, aq, 0, 0, 0);
        if (col < 8) {
            #pragma unroll
            for (int r = 0; r < 4; ++r) qB_w[(q4 * 4 + r) * 8 + col] = aq[r];
        }
    }

    // ---- double-buffered raw prefetch of k/pos/mask ----
    float4 kr[2][2][2]; float4 pr[2]; int4 mr[2];
    auto issue = [&](int b, int it2) {
        const size_t pair = (size_t)wid * 8 + it2;
        const float* kb = k + (pair * 16 + col) * 64 + q4 * 8;
        kr[b][0][0] = *(const float4*)kb;
        kr[b][0][1] = *(const float4*)(kb + 4);
        kr[b][1][0] = *(const float4*)(kb + 32);
        kr[b][1][1] = *(const float4*)(kb + 36);
        pr[b] = (q4 == 0) ? *(const float4*)(pos + (pair * 16 + col) * 4)
                          : make_float4(0.f, 0.f, 0.f, 0.f);
        mr[b] = *(const int4*)(mask + pair * 16 + q4 * 4);
    };
    issue(0, 0);

    #pragma unroll 2
    for (int it = 0; it < 8; ++it) {
        const int b = it & 1;
        if (it < 7) issue(b ^ 1, it + 1);
        const int rowbase = it * 2 + (q4 >> 1);   // wave-local bn of my C-rows

        // ---- hp = relu(pos.pos_w1 + b1) via MFMA (K=4) ----
        bf16x8 Apos = z;
        if (q4 == 0) {
            float t4[8] = {pr[b].x, pr[b].y, pr[b].z, pr[b].w, 0.f, 0.f, 0.f, 0.f};
            Apos = pack8(t4);
        }
        f32x4 hpc = {0.f, 0.f, 0.f, 0.f};
        hpc = __builtin_amdgcn_mfma_f32_16x16x32_bf16(Apos, Bpw1, hpc, 0, 0, 0);
        if (col < 8) {
            #pragma unroll
            for (int r = 0; r < 4; ++r)
                hp_w[(q4 * 4 + r) * 8 + col] = f2bf(fmaxf(hpc[r] + b1c, 0.f));
        }

        // ---- k A-frags (truncating pack) ----
        bf16x8 Ak0 = pack8t(kr[b][0][0], kr[b][0][1]);
        bf16x8 Ak1 = pack8t(kr[b][1][0], kr[b][1][1]);

        bf16x8 Ahp = z;
        if (lane < 16) Ahp = *(const bf16x8*)&hp_w[lane * 8];

        // ---- hid = k.At - q.Bqt + hp.Ct + c0 ; relu ; stage bf16 ----
        const float qbc = (col < 8) ? qB_w[rowbase * 8 + col] : 0.f;
        f32x4 acch = {0.f, 0.f, 0.f, 0.f};
        acch = __builtin_amdgcn_mfma_f32_16x16x32_bf16(Ak0, Bh[0], acch, 0, 0, 0);
        acch = __builtin_amdgcn_mfma_f32_16x16x32_bf16(Ak1, Bh[1], acch, 0, 0, 0);
        acch = __builtin_amdgcn_mfma_f32_16x16x32_bf16(Ahp, Bct,  acch, 0, 0, 0);
        if (col < 8) {
            #pragma unroll
            for (int r = 0; r < 4; ++r)
                rh_w[(q4 * 4 + r) * 8 + col] = f2bf(fmaxf(acch[r] + qbc + c0r, 0.f));
        }
        bf16x8 Arh = z;
        if (lane < 16) Arh = *(const bf16x8*)&rh_w[lane * 8];

        // ---- per d-tile: vh+pv, logits, masked softmax over v, combine ----
        #pragma unroll
        for (int t = 0; t < 4; ++t) {
            f32x4 av = {0.f, 0.f, 0.f, 0.f};
            av = __builtin_amdgcn_mfma_f32_16x16x32_bf16(Ak0, Bv[t][0], av, 0, 0, 0);
            av = __builtin_amdgcn_mfma_f32_16x16x32_bf16(Ak1, Bv[t][1], av, 0, 0, 0);
            av = __builtin_amdgcn_mfma_f32_16x16x32_bf16(Ahp, Bpw2[t],  av, 0, 0, 0);
            f32x4 al = {0.f, 0.f, 0.f, 0.f};
            al = __builtin_amdgcn_mfma_f32_16x16x32_bf16(Arh, Bw2[t], al, 0, 0, 0);

            float att[4];
            att[0] = mr[b].x ? (al[0] + b2a4[t]) : -1e9f;
            att[1] = mr[b].y ? (al[1] + b2a4[t]) : -1e9f;
            att[2] = mr[b].z ? (al[2] + b2a4[t]) : -1e9f;
            att[3] = mr[b].w ? (al[3] + b2a4[t]) : -1e9f;

            float mp = fmaxf(fmaxf(att[0], att[1]), fmaxf(att[2], att[3]));
            float mm = fmaxf(mp, __shfl_xor(mp, 16));
            float e0 = __expf(att[0] - mm), e1 = __expf(att[1] - mm);
            float e2 = __expf(att[2] - mm), e3 = __expf(att[3] - mm);
            float sp = e0 + e1 + e2 + e3;
            float ss = sp + __shfl_xor(sp, 16);
            float xp = e0 * (av[0] + sb4[t]) + e1 * (av[1] + sb4[t])
                     + e2 * (av[2] + sb4[t]) + e3 * (av[3] + sb4[t]);
            float x = (xp + __shfl_xor(xp, 16)) * __builtin_amdgcn_rcpf(ss);
            if ((q4 & 1) == 0)
                x_w[rowbase * 72 + t * 16 + col] = f2bf(x);
        }
    }

    // ---- OUT: out[16 x 64] = x.out_w + out_b over the wave's 16 bn ----
    bf16x8 Ax[2];
    #pragma unroll
    for (int c = 0; c < 2; ++c)
        Ax[c] = *(const bf16x8*)&x_w[col * 72 + c * 32 + q4 * 8];
    #pragma unroll
    for (int t = 0; t < 4; ++t) {
        bf16x8 Bo0 = *(const bf16x8*)&pk[PB_OWT + (t * 16 + col) * 64 + q4 * 8];
        bf16x8 Bo1 = *(const bf16x8*)&pk[PB_OWT + (t * 16 + col) * 64 + 32 + q4 * 8];
        f32x4 a = {0.f, 0.f, 0.f, 0.f};
        a = __builtin_amdgcn_mfma_f32_16x16x32_bf16(Ax[0], Bo0, a, 0, 0, 0);
        a = __builtin_amdgcn_mfma_f32_16x16x32_bf16(Ax[1], Bo1, a, 0, 0, 0);
        #pragma unroll
        for (int r = 0; r < 4; ++r)
            out[((size_t)wid * 16 + q4 * 4 + r) * 64 + t * 16 + col] = a[r] + ob4[t];
    }
}

extern "C" void kernel_launch(void* const* d_in, const int* in_sizes, int n_in,
                              void* d_out, int out_size, void* d_ws, size_t ws_size,
                              hipStream_t stream) {
    const float* q        = (const float*)d_in[0];
    const float* k        = (const float*)d_in[1];
    const float* pos      = (const float*)d_in[2];
    const float* strength = (const float*)d_in[3];
    const float* q_tbl    = (const float*)d_in[4];
    const float* k_tbl    = (const float*)d_in[5];
    const float* v_tbl    = (const float*)d_in[6];
    const float* pos_w1   = (const float*)d_in[7];
    const float* pos_b1   = (const float*)d_in[8];
    const float* pos_w2   = (const float*)d_in[9];
    const float* pos_b2   = (const float*)d_in[10];
    const float* attn_w1  = (const float*)d_in[11];
    const float* attn_b1  = (const float*)d_in[12];
    const float* attn_w2  = (const float*)d_in[13];
    const float* attn_b2  = (const float*)d_in[14];
    const float* out_w    = (const float*)d_in[15];
    const float* out_b    = (const float*)d_in[16];
    const float* str_w    = (const float*)d_in[17];
    const float* str_b    = (const float*)d_in[18];
    const int*   mask     = (const int*)d_in[19];
    const int*   embed    = (const int*)d_in[20];
    float* ws  = (float*)d_ws;
    float* out = (float*)d_out;

    hipLaunchKernelGGL(precompute_kernel, dim3(6), dim3(256), 0, stream,
                       strength, str_w, str_b, q_tbl, k_tbl, attn_w1, attn_b1,
                       pos_w2, pos_b2, embed, ws);
    hipLaunchKernelGGL(pack_kernel, dim3((PB_END + 255) / 256), dim3(256), 0, stream,
                       v_tbl, pos_w1, pos_w2, attn_w2, out_w, embed, ws);
    hipLaunchKernelGGL(attn2d_main, dim3(1024), dim3(256), 0, stream,
                       q, k, pos, pos_b1, pos_b2, attn_b2, out_b, mask, ws, out);
}